// Round 15
// baseline (527.084 us; speedup 1.0000x reference)
//
#include <hip/hip_runtime.h>

typedef unsigned short u16;
typedef short short8 __attribute__((ext_vector_type(8)));
typedef short short4b __attribute__((ext_vector_type(4)));
typedef float f32x4 __attribute__((ext_vector_type(4)));
typedef u16 us4 __attribute__((ext_vector_type(4)));
typedef unsigned u32x2 __attribute__((ext_vector_type(2)));

#define DIM   1536
#define NH    12
#define HD    128
#define SQ_   2640
#define SPAD  2688
#define PAST_ 10560
#define LTOT  13200
#define LPAD  13248

__device__ __forceinline__ u16 f2bf(float f){
  unsigned u = __builtin_bit_cast(unsigned, f);
  u += 0x7fffu + ((u >> 16) & 1u);
  return (u16)(u >> 16);
}
__device__ __forceinline__ float bf2f(u16 h){
  unsigned u = ((unsigned)h) << 16;
  return __builtin_bit_cast(float, u);
}
__device__ __forceinline__ unsigned cvtpk_bf16(float lo, float hi){
  unsigned r;
  asm("v_cvt_pk_bf16_f32 %0, %1, %2" : "=v"(r) : "v"(lo), "v"(hi));
  return r;
}
__device__ __forceinline__ void gload_lds16(const void* g, void* l){
  __builtin_amdgcn_global_load_lds(
      (const __attribute__((address_space(1))) void*)g,
      (__attribute__((address_space(3))) void*)l, 16, 0, 0);
}
// 16x16x16 bf16 MFMA (k=16): lane l holds X[l&15][(l>>4)*4 + e].
__device__ __forceinline__ f32x4 mfma16(short4b a, short4b b, f32x4 c){
#if __has_builtin(__builtin_amdgcn_mfma_f32_16x16x16bf16_1k)
  return __builtin_amdgcn_mfma_f32_16x16x16bf16_1k(a, b, c, 0, 0, 0);
#else
  asm("v_mfma_f32_16x16x16_bf16 %0, %1, %2, %0" : "+v"(c) : "v"(a), "v"(b));
  return c;
#endif
}

// ---------------- prep kernels (fused) ----------------
__global__ void k_cvt4(const float* __restrict__ s0, const float* __restrict__ s1,
                       const float* __restrict__ s2, const float* __restrict__ s3,
                       u16* __restrict__ d0, u16* __restrict__ d1,
                       u16* __restrict__ d2, u16* __restrict__ d3, int n4){
  int i = blockIdx.x * 256 + threadIdx.x;
  int y = blockIdx.y;
  const float* s = (y==0)?s0:((y==1)?s1:((y==2)?s2:s3));
  u16* d = (y==0)?d0:((y==1)?d1:((y==2)?d2:d3));
  if (i < n4){
    float4 f = ((const float4*)s)[i];
    us4 u; u[0]=f2bf(f.x); u[1]=f2bf(f.y); u[2]=f2bf(f.z); u[3]=f2bf(f.w);
    ((us4*)d)[i] = u;
  }
}

// x -> AB (bf16, pad rows zeroed) AND zero QL's pad rows
__global__ void k_prep_x(const float* __restrict__ x, u16* __restrict__ AB,
                         u16* __restrict__ QLpad){
  int i = blockIdx.x * 256 + threadIdx.x;
  if (i < SPAD*DIM/4){
    int e = i * 4;
    us4 u; u[0]=0; u[1]=0; u[2]=0; u[3]=0;
    if (e < SQ_*DIM){
      float4 f = ((const float4*)x)[i];
      u[0]=f2bf(f.x); u[1]=f2bf(f.y); u[2]=f2bf(f.z); u[3]=f2bf(f.w);
    }
    ((us4*)AB)[i] = u;
  } else {
    int k = i - SPAD*DIM/4;
    if (k < (SPAD-SQ_)*DIM/4){
      us4 u; u[0]=0; u[1]=0; u[2]=0; u[3]=0;
      ((us4*)QLpad)[k] = u;
    }
  }
}

__global__ void k_prep_kv(const float* __restrict__ ck, const float* __restrict__ cv,
                          u16* __restrict__ KA, u16* __restrict__ VA, int n4){
  int i = blockIdx.x * 256 + threadIdx.x;
  if (i >= n4) return;
  const float* src = blockIdx.y ? cv : ck;
  u16* dst = blockIdx.y ? VA : KA;
  int e = i * 4;
  if (e < PAST_*DIM){
    float4 f = ((const float4*)src)[i];
    us4 u; u[0]=f2bf(f.x); u[1]=f2bf(f.y); u[2]=f2bf(f.z); u[3]=f2bf(f.w);
    ((us4*)dst)[i] = u;
  } else {
    us4 u; u[0]=0; u[1]=0; u[2]=0; u[3]=0;
    ((us4*)dst)[i - PAST_*DIM/4 + LTOT*DIM/4] = u;
  }
}

// ---------------- fused QKV GEMM (BK=64, XOR-swizzled staging, 1D XCD grid) ----------------
__global__ __launch_bounds__(256) void gemm_qkv(
  const u16* __restrict__ A,
  const u16* __restrict__ W0, const u16* __restrict__ W1, const u16* __restrict__ W2,
  const float* __restrict__ b0, const float* __restrict__ b1, const float* __restrict__ b2,
  u16* __restrict__ QL, u16* __restrict__ KL, u16* __restrict__ VA)
{
  __shared__ __align__(16) u16 As[8192];   // [128 rows][64 cols], XOR key (r&7)<<4 on byte col
  __shared__ __align__(16) u16 Bs[8192];
  // nwg=756: q=94,r=4 -> xcd<4 get 95 blocks, else 94 (m204 bijective)
  int b = blockIdx.x;
  int xcd = b & 7, idx = b >> 3;
  int wg = (xcd < 4 ? xcd*95 : 380 + (xcd-4)*94) + idx;
  int mt = wg % 21, nt = wg / 21;
  int tid = threadIdx.x, lane = tid & 63, w = tid >> 6;
  int wr = w >> 1, wc = w & 1;
  int which = nt / 12;
  const u16*  Bp = which==0 ? W0 : (which==1 ? W1 : W2);
  const float* bp = which==0 ? b0 : (which==1 ? b1 : b2);
  int nloc = (nt % 12) * 128;
  f32x4 acc[4][4];
  #pragma unroll
  for (int i=0;i<4;i++)
    #pragma unroll
    for (int j=0;j<4;j++) acc[i][j] = (f32x4){0.f,0.f,0.f,0.f};

  for (int k0 = 0; k0 < DIM; k0 += 64){
    #pragma unroll
    for (int p=0;p<4;p++){
      int e = (p*256 + tid) * 8;
      int r = e >> 6;
      int c2 = (e & 63) << 1;                 // byte col within 128B row
      int sb = c2 ^ ((r & 7) << 4);           // pre-swizzled source (rule #21)
      gload_lds16(A  + (size_t)(mt*128 + r)*DIM + k0 + (sb>>1), (char*)As + p*4096 + (w<<10));
      gload_lds16(Bp + (size_t)(nloc   + r)*DIM + k0 + (sb>>1), (char*)Bs + p*4096 + (w<<10));
    }
    __syncthreads();
    #pragma unroll
    for (int kk=0;kk<2;kk++){
      short8 af[4], bfr[4];
      #pragma unroll
      for (int i=0;i<4;i++){
        int rowa = wr*64 + i*16 + (lane&15);
        int cba = (kk*64 + (lane>>4)*16) ^ ((rowa & 7) << 4);
        af[i] = *(const short8*)((const char*)As + rowa*128 + cba);
        int rowb = wc*64 + i*16 + (lane&15);
        int cbb = (kk*64 + (lane>>4)*16) ^ ((rowb & 7) << 4);
        bfr[i] = *(const short8*)((const char*)Bs + rowb*128 + cbb);
      }
      #pragma unroll
      for (int i=0;i<4;i++)
        #pragma unroll
        for (int j=0;j<4;j++)
          acc[i][j] = __builtin_amdgcn_mfma_f32_16x16x32_bf16(af[i], bfr[j], acc[i][j], 0,0,0);
    }
    __syncthreads();
  }
  int rbase = mt*128 + wr*64;
  int cbase = nloc + wc*64;
  #pragma unroll
  for (int j=0;j<4;j++){
    int col = cbase + j*16 + (lane&15);
    float bb = bp[col];
    #pragma unroll
    for (int i=0;i<4;i++){
      #pragma unroll
      for (int q=0;q<4;q++){
        int row = rbase + i*16 + (lane>>4)*4 + q;
        if (row < SQ_){
          u16 uv = f2bf(acc[i][j][q] + bb);
          if (which==0)      QL[(size_t)row*DIM + col] = uv;
          else if (which==1) KL[(size_t)row*DIM + col] = uv;
          else               VA[(size_t)(PAST_ + row)*DIM + col] = uv;
        }
      }
    }
  }
}

// ---------------- output GEMM (BK=64, XOR-swizzled staging, 1D XCD grid) ----------------
__global__ __launch_bounds__(256) void gemm_out(
  const u16* __restrict__ A, const u16* __restrict__ W,
  const float* __restrict__ bias, float* __restrict__ out)
{
  __shared__ __align__(16) u16 As[8192];
  __shared__ __align__(16) u16 Bs[8192];
  // nwg=252: q=31,r=4 -> xcd<4 get 32 blocks, else 31
  int b = blockIdx.x;
  int xcd = b & 7, idx = b >> 3;
  int wg = (xcd < 4 ? xcd*32 : 128 + (xcd-4)*31) + idx;
  int mt = wg % 21, nt = wg / 21;
  int tid = threadIdx.x, lane = tid & 63, w = tid >> 6;
  int wr = w >> 1, wc = w & 1;
  int nloc = nt * 128;
  f32x4 acc[4][4];
  #pragma unroll
  for (int i=0;i<4;i++)
    #pragma unroll
    for (int j=0;j<4;j++) acc[i][j] = (f32x4){0.f,0.f,0.f,0.f};

  for (int k0 = 0; k0 < DIM; k0 += 64){
    #pragma unroll
    for (int p=0;p<4;p++){
      int e = (p*256 + tid) * 8;
      int r = e >> 6;
      int c2 = (e & 63) << 1;
      int sb = c2 ^ ((r & 7) << 4);
      gload_lds16(A + (size_t)(mt*128 + r)*DIM + k0 + (sb>>1), (char*)As + p*4096 + (w<<10));
      gload_lds16(W + (size_t)(nloc   + r)*DIM + k0 + (sb>>1), (char*)Bs + p*4096 + (w<<10));
    }
    __syncthreads();
    #pragma unroll
    for (int kk=0;kk<2;kk++){
      short8 af[4], bfr[4];
      #pragma unroll
      for (int i=0;i<4;i++){
        int rowa = wr*64 + i*16 + (lane&15);
        int cba = (kk*64 + (lane>>4)*16) ^ ((rowa & 7) << 4);
        af[i] = *(const short8*)((const char*)As + rowa*128 + cba);
        int rowb = wc*64 + i*16 + (lane&15);
        int cbb = (kk*64 + (lane>>4)*16) ^ ((rowb & 7) << 4);
        bfr[i] = *(const short8*)((const char*)Bs + rowb*128 + cbb);
      }
      #pragma unroll
      for (int i=0;i<4;i++)
        #pragma unroll
        for (int j=0;j<4;j++)
          acc[i][j] = __builtin_amdgcn_mfma_f32_16x16x32_bf16(af[i], bfr[j], acc[i][j], 0,0,0);
    }
    __syncthreads();
  }
  int rbase = mt*128 + wr*64;
  int cbase = nloc + wc*64;
  #pragma unroll
  for (int j=0;j<4;j++){
    int col = cbase + j*16 + (lane&15);
    float bb = bias[col];
    #pragma unroll
    for (int i=0;i<4;i++){
      #pragma unroll
      for (int q=0;q<4;q++){
        int row = rbase + i*16 + (lane>>4)*4 + q;
        if (row < SQ_) out[(size_t)row*DIM + col] = acc[i][j][q] + bb;
      }
    }
  }
}

// ---------------- RMSNorm + RoPE (q and k fused: trig computed once) ----------------
// q path pre-scaled by log2(e)/sqrt(HD): attn logits land in exp2 domain.
__global__ __launch_bounds__(256) void norm_rope(
  const u16* __restrict__ QL, const u16* __restrict__ KL,
  const float* __restrict__ freqs, const float* __restrict__ gq, const float* __restrict__ gk,
  const int* __restrict__ cs,
  u16* __restrict__ Qout, u16* __restrict__ KAout)
{
  int s = blockIdx.x;
  int tid = threadIdx.x;
  const u16* srcq = QL + (size_t)s*DIM + tid*6;
  const u16* srck = KL + (size_t)s*DIM + tid*6;
  float yq[6], yk[6];
  #pragma unroll
  for (int t=0;t<6;t++){ yq[t] = bf2f(srcq[t]); yk[t] = bf2f(srck[t]); }
  float ssq = 0.f, ssk = 0.f;
  #pragma unroll
  for (int t=0;t<6;t++){ ssq += yq[t]*yq[t]; ssk += yk[t]*yk[t]; }
  for (int mk=1; mk<64; mk<<=1){ ssq += __shfl_xor(ssq, mk); ssk += __shfl_xor(ssk, mk); }
  __shared__ float redq[4], redk[4];
  if ((tid & 63) == 0){ redq[tid>>6] = ssq; redk[tid>>6] = ssk; }
  __syncthreads();
  float rnq = rsqrtf((redq[0]+redq[1]+redq[2]+redq[3]) * (1.0f/1536.0f) + 1e-6f)
            * 0.12752961954336302f;   // 1/sqrt(128) * log2(e)
  float rnk = rsqrtf((redk[0]+redk[1]+redk[2]+redk[3]) * (1.0f/1536.0f) + 1e-6f);
  const float* gqp = gq + tid*6;
  const float* gkp = gk + tid*6;
  int pos = cs[0] + s;
  int tpos = pos / 880, rem = pos % 880;
  int hh = rem / 40, wp = rem % 40;
  u16 ovq[6], ovk[6];
  #pragma unroll
  for (int pi=0; pi<3; pi++){
    int p = tid*3 + pi;
    int i = p & 63;
    int fr = (i < 22) ? tpos : ((i < 43) ? hh : wp);
    float ang = freqs[fr*64 + i];
    float sn, c;
    sincosf(ang, &sn, &c);
    float eq  = yq[pi*2]   * rnq * gqp[pi*2];
    float oq  = yq[pi*2+1] * rnq * gqp[pi*2+1];
    ovq[pi*2]   = f2bf(eq*c - oq*sn);
    ovq[pi*2+1] = f2bf(oq*c + eq*sn);
    float ek  = yk[pi*2]   * rnk * gkp[pi*2];
    float ok  = yk[pi*2+1] * rnk * gkp[pi*2+1];
    ovk[pi*2]   = f2bf(ek*c - ok*sn);
    ovk[pi*2+1] = f2bf(ok*c + ek*sn);
  }
  u16* dq = Qout  + (size_t)s*DIM + tid*6;
  u16* dk = KAout + (size_t)(PAST_ + s)*DIM + tid*6;
  #pragma unroll
  for (int t=0;t<6;t++){ dq[t] = ovq[t]; dk[t] = ovk[t]; }
}

// ---------------- flash attention (r14 verbatim: XCD-grouped 1D grid) ----------------
__global__ __launch_bounds__(256, 2) void attn(
  const u16* __restrict__ Qf, const u16* __restrict__ KA,
  const u16* __restrict__ VA, u16* __restrict__ OP, float* __restrict__ ML)
{
  __shared__ __align__(16) u16 Ks[2][64*128];   // [kv][d], XOR key (kv&7)<<4
  __shared__ __align__(16) u16 Vt[2][128*64];   // [d][kv], XOR key ((d&7)<<4)|(((d>>3)&1)<<3)
  int bid = blockIdx.x;
  int wid = (bid & 7) * 63 + (bid >> 3);        // XCD-grouped work id
  int qt = wid % 21;
  int hz = wid / 21;
  int h = hz % 12;
  int z = hz / 12;
  int tid = threadIdx.x, lane = tid & 63, w = tid >> 6;
  int g = lane >> 4, q = lane & 15;
  int qrow0 = qt*128 + w*32;
  int kvbeg = z ? 6656 : 0;
  int kvend = z ? LPAD : 6656;
  int c0 = (tid >> 4) << 3;
  int r0 = (tid & 15) << 2;

  short8 qa[2][4];
  #pragma unroll
  for (int cq=0;cq<2;cq++){
    const u16* qb = Qf + (size_t)(qrow0 + cq*16 + q)*DIM + h*HD + g*8;
    #pragma unroll
    for (int kt=0;kt<4;kt++) qa[cq][kt] = *(const short8*)(qb + kt*32);
  }
  f32x4 o[2][8];
  #pragma unroll
  for (int cq=0;cq<2;cq++)
    #pragma unroll
    for (int dt=0;dt<8;dt++) o[cq][dt] = (f32x4){0.f,0.f,0.f,0.f};
  float m[2] = {-1e30f,-1e30f};
  float l[2] = {0.f,0.f};

  auto stageK = [&](int kv0, u16* dK){
    #pragma unroll
    for (int p=0;p<4;p++){
      int e = w*2048 + p*512 + lane*8;
      int r = e >> 7;
      int bcol = (e & 127) << 1;
      int sb = bcol ^ ((r & 7) << 4);
      gload_lds16(KA + (size_t)(kv0 + r)*DIM + h*HD + (sb>>1),
                  (char*)dK + w*4096 + p*1024);
    }
  };
  auto loadV = [&](int kv0, short8* vr){
    const u16* vs = VA + (size_t)(kv0 + r0)*DIM + h*HD + c0;
    vr[0] = *(const short8*)(vs);
    vr[1] = *(const short8*)(vs + DIM);
    vr[2] = *(const short8*)(vs + 2*DIM);
    vr[3] = *(const short8*)(vs + 3*DIM);
  };
  auto writeVt = [&](u16* dV, short8* vr){
    #pragma unroll
    for (int j=0;j<8;j++){
      int d = c0 + j;
      int key = ((d & 7) << 4) | (((d >> 3) & 1) << 3);
      int off = d*128 + ((r0*2) ^ key);
      us4 pk; pk[0]=(u16)vr[0][j]; pk[1]=(u16)vr[1][j]; pk[2]=(u16)vr[2][j]; pk[3]=(u16)vr[3][j];
      *(us4*)((char*)dV + off) = pk;
    }
  };

  short8 vr[4];
  int cur = 0;
  // prologue: stage tile 0
  stageK(kvbeg, &Ks[0][0]);
  loadV(kvbeg, vr);
  writeVt(&Vt[0][0], vr);
  __syncthreads();

  for (int kv0 = kvbeg; kv0 < kvend; kv0 += 64){
    int nxt = kv0 + 64;
    bool has_next = nxt < kvend;
    // --- issue next-tile staging BEFORE compute (latency hides under MFMA/VALU) ---
    if (has_next){
      stageK(nxt, &Ks[cur^1][0]);
      loadV(nxt, vr);
    }
    // --- QK^T swapped: D[kv][q] ---
    f32x4 s4[2][4];
    #pragma unroll
    for (int cq=0;cq<2;cq++)
      #pragma unroll
      for (int ct=0;ct<4;ct++) s4[cq][ct] = (f32x4){0.f,0.f,0.f,0.f};
    const u16* ksb = &Ks[cur][0];
    __builtin_amdgcn_s_setprio(1);
    #pragma unroll
    for (int ct=0;ct<4;ct++){
      int row = ct*16 + q;
      int rbyte = row*256, sw = (row & 7) << 4;
      #pragma unroll
      for (int kt=0;kt<4;kt++){
        int b = (kt*64 + (g<<4)) ^ sw;
        short8 kb = *(const short8*)((const char*)ksb + rbyte + b);
        s4[0][ct] = __builtin_amdgcn_mfma_f32_16x16x32_bf16(kb, qa[0][kt], s4[0][ct], 0,0,0);
        s4[1][ct] = __builtin_amdgcn_mfma_f32_16x16x32_bf16(kb, qa[1][kt], s4[1][ct], 0,0,0);
      }
    }
    __builtin_amdgcn_s_setprio(0);
    // --- tail mask: kv = kv0 + ct*16 + g*4 + j ---
    if (kv0 + 64 > LTOT){
      #pragma unroll
      for (int ct=0;ct<4;ct++)
        #pragma unroll
        for (int j=0;j<4;j++)
          if (kv0 + ct*16 + g*4 + j >= LTOT){ s4[0][ct][j] = -1e30f; s4[1][ct][j] = -1e30f; }
    }
    // --- row max (max3-friendly triples) + defer-max (T13, THR=8) ---
    float rm[2];
    #pragma unroll
    for (int cq=0;cq<2;cq++){
      float a0 = fmaxf(fmaxf(s4[cq][0][0], s4[cq][0][1]), s4[cq][0][2]);
      float a1 = fmaxf(fmaxf(s4[cq][0][3], s4[cq][1][0]), s4[cq][1][1]);
      float a2 = fmaxf(fmaxf(s4[cq][1][2], s4[cq][1][3]), s4[cq][2][0]);
      float a3 = fmaxf(fmaxf(s4[cq][2][1], s4[cq][2][2]), s4[cq][2][3]);
      float a4 = fmaxf(fmaxf(s4[cq][3][0], s4[cq][3][1]), s4[cq][3][2]);
      float r_ = fmaxf(fmaxf(a0, a1), fmaxf(fmaxf(a2, a3), fmaxf(a4, s4[cq][3][3])));
      r_ = fmaxf(r_, __shfl_xor(r_, 16));
      r_ = fmaxf(r_, __shfl_xor(r_, 32));
      rm[cq] = r_;
    }
    if (__any((rm[0] > m[0]+8.f) | (rm[1] > m[1]+8.f))){
      #pragma unroll
      for (int cq=0;cq<2;cq++){
        float mn = fmaxf(m[cq], rm[cq]);
        float al = exp2f(m[cq] - mn);
        m[cq] = mn;
        l[cq] *= al;
        #pragma unroll
        for (int dt=0;dt<8;dt++){
          f32x4 t = o[cq][dt];
          t[0]*=al; t[1]*=al; t[2]*=al; t[3]*=al;
          o[cq][dt] = t;
        }
      }
    }
    // --- exp2 + cvt_pk pack into PV B-frags + row sum ---
    short4b pb[2][4];
    #pragma unroll
    for (int cq=0;cq<2;cq++){
      float rs = 0.f;
      #pragma unroll
      for (int ct=0;ct<4;ct++){
        float e0 = exp2f(s4[cq][ct][0] - m[cq]);
        float e1 = exp2f(s4[cq][ct][1] - m[cq]);
        float e2 = exp2f(s4[cq][ct][2] - m[cq]);
        float e3 = exp2f(s4[cq][ct][3] - m[cq]);
        rs += (e0 + e1) + (e2 + e3);
        u32x2 pw = { cvtpk_bf16(e0, e1), cvtpk_bf16(e2, e3) };
        pb[cq][ct] = __builtin_bit_cast(short4b, pw);
      }
      rs += __shfl_xor(rs, 16);
      rs += __shfl_xor(rs, 32);
      l[cq] += rs;
    }
    // --- PV via 16x16x16: o[d][q] += V^T[d][kv] · P^T[q][kv] ---
    const u16* vtb = &Vt[cur][0];
    __builtin_amdgcn_s_setprio(1);
    #pragma unroll
    for (int dt=0;dt<8;dt++){
      int d = dt*16 + q;
      int key = ((d & 7) << 4) | (((d >> 3) & 1) << 3);
      int rbyte = d*128;
      #pragma unroll
      for (int ct=0;ct<4;ct++){
        int b = (ct*32 + (g<<3)) ^ key;
        short4b va_ = *(const short4b*)((const char*)vtb + rbyte + b);
        o[0][dt] = mfma16(va_, pb[0][ct], o[0][dt]);
        o[1][dt] = mfma16(va_, pb[1][ct], o[1][dt]);
      }
    }
    __builtin_amdgcn_s_setprio(0);
    // --- finish staging: write Vt(t+1) (compiler waits vmcnt on vr), one barrier ---
    if (has_next){
      writeVt(&Vt[cur^1][0], vr);
      __syncthreads();
      cur ^= 1;
    }
  }
  // --- store UNNORMALIZED partial (bf16 via cvt_pk) + (m,l) per q-row ---
  #pragma unroll
  for (int cq=0;cq<2;cq++){
    int row = qrow0 + cq*16 + q;
    size_t ob = ((size_t)(z*SPAD + row)*NH + h)*HD;
    #pragma unroll
    for (int dt=0;dt<8;dt++){
      u32x2 pw = { cvtpk_bf16(o[cq][dt][0], o[cq][dt][1]),
                   cvtpk_bf16(o[cq][dt][2], o[cq][dt][3]) };
      *(u32x2*)&OP[ob + dt*16 + g*4] = pw;
    }
    if (g == 0){
      size_t mb = ((size_t)(z*SPAD + row)*NH + h)*2;
      ML[mb] = m[cq]; ML[mb+1] = l[cq];
    }
  }
}

// ---------------- merge kv-split partials (flat grid-stride) ----------------
__global__ void merge_attn(const u16* __restrict__ OP, const float* __restrict__ ML,
                           u16* __restrict__ AB)
{
  const int total = SQ_ * NH * HD;
  for (int e = blockIdx.x * 256 + threadIdx.x; e < total; e += gridDim.x * 256){
    int s = e / (NH*HD);
    int r = e - s*(NH*HD);
    int h = r >> 7;
    int d = r & 127;
    size_t i1 = ((size_t)s*NH + h)*2;
    size_t i2 = ((size_t)(SPAD + s)*NH + h)*2;
    float m1 = ML[i1], l1 = ML[i1+1];
    float m2 = ML[i2], l2 = ML[i2+1];
    float M = fmaxf(m1, m2);
    float e1 = exp2f(m1 - M), e2 = exp2f(m2 - M);
    float den = 1.0f / (l1*e1 + l2*e2);
    float o1 = bf2f(OP[((size_t)s*NH + h)*HD + d]);
    float o2 = bf2f(OP[((size_t)(SPAD + s)*NH + h)*HD + d]);
    AB[(size_t)s*DIM + h*HD + d] = f2bf((o1*e1 + o2*e2) * den);
  }
}

// ---------------- launch ----------------
extern "C" void kernel_launch(void* const* d_in, const int* in_sizes, int n_in,
                              void* d_out, int out_size, void* d_ws, size_t ws_size,
                              hipStream_t stream) {
  (void)in_sizes; (void)n_in; (void)out_size; (void)ws_size;
  const float* x    = (const float*)d_in[0];
  const float* freqs= (const float*)d_in[1];
  const float* ck   = (const float*)d_in[2];
  const float* cv   = (const float*)d_in[3];
  const float* Wq   = (const float*)d_in[4];
  const float* bq   = (const float*)d_in[5];
  const float* Wk   = (const float*)d_in[6];
  const float* bk   = (const float*)d_in[7];
  const float* Wv   = (const float*)d_in[8];
  const float* bv   = (const float*)d_in[9];
  const float* Wo   = (const float*)d_in[10];
  const float* bo   = (const float*)d_in[11];
  const float* gq   = (const float*)d_in[12];
  const float* gk   = (const float*)d_in[13];
  const int*   cs   = (const int*)d_in[14];
  float* out = (float*)d_out;
  char* ws = (char*)d_ws;

  u16* AB  = (u16*)(ws);                      // 8,257,536 (x_bf16 -> attn out)
  u16* Wb3 = (u16*)(ws + 8257536);            // 4,718,592
  u16* QL  = (u16*)(ws + 12976128);           // 8,257,536
  u16* KA  = (u16*)(ws + 21233664);           // 40,697,856
  u16* VA  = (u16*)(ws + 61931520);           // 40,697,856
  u16* Wb0 = (u16*)(ws + 102629376);
  u16* Wb1 = (u16*)(ws + 107347968);
  u16* Wb2 = (u16*)(ws + 112066560);
  u16* KL  = (u16*)(ws + 116785152);          // ends 124,895,232
  u16*   OP = (u16*)(ws + 102629376);         // 16,515,072 (2 x 2688 x 12 x 128 bf16)
  float* ML = (float*)(ws + 119144448);       // 516,096

  k_cvt4<<<dim3(2304,4), 256, 0, stream>>>(Wq, Wk, Wv, Wo, Wb0, Wb1, Wb2, Wb3, 589824);
  k_prep_x<<<4104, 256, 0, stream>>>(x, AB, QL + (size_t)SQ_*DIM);
  k_prep_kv<<<dim3(15912,2), 256, 0, stream>>>(ck, cv, KA, VA, 4073472);

  gemm_qkv<<<756, 256, 0, stream>>>(AB, Wb0, Wb1, Wb2, bq, bk, bv, QL, KL, VA);
  norm_rope<<<2640, 256, 0, stream>>>(QL, KL, freqs, gq, gk, cs, QL, KA);
  attn<<<504, 256, 0, stream>>>(QL, KA, VA, OP, ML);
  merge_attn<<<2048, 256, 0, stream>>>(OP, ML, AB);
  gemm_out<<<252, 256, 0, stream>>>(AB, Wb3, bo, out);
}

// Round 16
// 499.030 us; speedup vs baseline: 1.0562x; 1.0562x over previous
//
#include <hip/hip_runtime.h>

typedef unsigned short u16;
typedef short short8 __attribute__((ext_vector_type(8)));
typedef short short4b __attribute__((ext_vector_type(4)));
typedef float f32x4 __attribute__((ext_vector_type(4)));
typedef u16 us4 __attribute__((ext_vector_type(4)));
typedef unsigned u32x2 __attribute__((ext_vector_type(2)));

#define DIM   1536
#define NH    12
#define HD    128
#define SQ_   2640
#define SPAD  2688
#define PAST_ 10560
#define LTOT  13200
#define LPAD  13248

__device__ __forceinline__ u16 f2bf(float f){
  unsigned u = __builtin_bit_cast(unsigned, f);
  u += 0x7fffu + ((u >> 16) & 1u);
  return (u16)(u >> 16);
}
__device__ __forceinline__ float bf2f(u16 h){
  unsigned u = ((unsigned)h) << 16;
  return __builtin_bit_cast(float, u);
}
__device__ __forceinline__ unsigned cvtpk_bf16(float lo, float hi){
  unsigned r;
  asm("v_cvt_pk_bf16_f32 %0, %1, %2" : "=v"(r) : "v"(lo), "v"(hi));
  return r;
}
__device__ __forceinline__ void gload_lds16(const void* g, void* l){
  __builtin_amdgcn_global_load_lds(
      (const __attribute__((address_space(1))) void*)g,
      (__attribute__((address_space(3))) void*)l, 16, 0, 0);
}
// 16x16x16 bf16 MFMA (k=16): lane l holds X[l&15][(l>>4)*4 + e].
__device__ __forceinline__ f32x4 mfma16(short4b a, short4b b, f32x4 c){
#if __has_builtin(__builtin_amdgcn_mfma_f32_16x16x16bf16_1k)
  return __builtin_amdgcn_mfma_f32_16x16x16bf16_1k(a, b, c, 0, 0, 0);
#else
  asm("v_mfma_f32_16x16x16_bf16 %0, %1, %2, %0" : "+v"(c) : "v"(a), "v"(b));
  return c;
#endif
}

// ---------------- prep kernels (fused) ----------------
__global__ void k_cvt4(const float* __restrict__ s0, const float* __restrict__ s1,
                       const float* __restrict__ s2, const float* __restrict__ s3,
                       u16* __restrict__ d0, u16* __restrict__ d1,
                       u16* __restrict__ d2, u16* __restrict__ d3, int n4){
  int i = blockIdx.x * 256 + threadIdx.x;
  int y = blockIdx.y;
  const float* s = (y==0)?s0:((y==1)?s1:((y==2)?s2:s3));
  u16* d = (y==0)?d0:((y==1)?d1:((y==2)?d2:d3));
  if (i < n4){
    float4 f = ((const float4*)s)[i];
    us4 u; u[0]=f2bf(f.x); u[1]=f2bf(f.y); u[2]=f2bf(f.z); u[3]=f2bf(f.w);
    ((us4*)d)[i] = u;
  }
}

// x -> AB (bf16, pad rows zeroed) AND zero QL's pad rows
__global__ void k_prep_x(const float* __restrict__ x, u16* __restrict__ AB,
                         u16* __restrict__ QLpad){
  int i = blockIdx.x * 256 + threadIdx.x;
  if (i < SPAD*DIM/4){
    int e = i * 4;
    us4 u; u[0]=0; u[1]=0; u[2]=0; u[3]=0;
    if (e < SQ_*DIM){
      float4 f = ((const float4*)x)[i];
      u[0]=f2bf(f.x); u[1]=f2bf(f.y); u[2]=f2bf(f.z); u[3]=f2bf(f.w);
    }
    ((us4*)AB)[i] = u;
  } else {
    int k = i - SPAD*DIM/4;
    if (k < (SPAD-SQ_)*DIM/4){
      us4 u; u[0]=0; u[1]=0; u[2]=0; u[3]=0;
      ((us4*)QLpad)[k] = u;
    }
  }
}

__global__ void k_prep_kv(const float* __restrict__ ck, const float* __restrict__ cv,
                          u16* __restrict__ KA, u16* __restrict__ VA, int n4){
  int i = blockIdx.x * 256 + threadIdx.x;
  if (i >= n4) return;
  const float* src = blockIdx.y ? cv : ck;
  u16* dst = blockIdx.y ? VA : KA;
  int e = i * 4;
  if (e < PAST_*DIM){
    float4 f = ((const float4*)src)[i];
    us4 u; u[0]=f2bf(f.x); u[1]=f2bf(f.y); u[2]=f2bf(f.z); u[3]=f2bf(f.w);
    ((us4*)dst)[i] = u;
  } else {
    us4 u; u[0]=0; u[1]=0; u[2]=0; u[3]=0;
    ((us4*)dst)[i - PAST_*DIM/4 + LTOT*DIM/4] = u;
  }
}

// ---------------- fused QKV GEMM (r14-verbatim: BK=32, 1D XCD grid) ----------------
__global__ __launch_bounds__(256) void gemm_qkv(
  const u16* __restrict__ A,
  const u16* __restrict__ W0, const u16* __restrict__ W1, const u16* __restrict__ W2,
  const float* __restrict__ b0, const float* __restrict__ b1, const float* __restrict__ b2,
  u16* __restrict__ QL, u16* __restrict__ KL, u16* __restrict__ VA)
{
  __shared__ __align__(16) u16 As[4096];
  __shared__ __align__(16) u16 Bs[4096];
  // nwg=756: q=94,r=4 -> xcd<4 get 95 blocks, else 94 (m204 bijective)
  int b = blockIdx.x;
  int xcd = b & 7, idx = b >> 3;
  int wg = (xcd < 4 ? xcd*95 : 380 + (xcd-4)*94) + idx;
  int mt = wg % 21, nt = wg / 21;
  int tid = threadIdx.x, lane = tid & 63, w = tid >> 6;
  int wr = w >> 1, wc = w & 1;
  int which = nt / 12;
  const u16*  Bp = which==0 ? W0 : (which==1 ? W1 : W2);
  const float* bp = which==0 ? b0 : (which==1 ? b1 : b2);
  int nloc = (nt % 12) * 128;
  f32x4 acc[4][4];
  #pragma unroll
  for (int i=0;i<4;i++)
    #pragma unroll
    for (int j=0;j<4;j++) acc[i][j] = (f32x4){0.f,0.f,0.f,0.f};

  for (int k0 = 0; k0 < DIM; k0 += 32){
    #pragma unroll
    for (int p=0;p<2;p++){
      int e = (p*256 + tid) * 8;
      int r = e >> 5, c = e & 31;
      gload_lds16(A  + (size_t)(mt*128 + r)*DIM + k0 + c, (char*)As + p*4096 + (w<<10));
      gload_lds16(Bp + (size_t)(nloc   + r)*DIM + k0 + c, (char*)Bs + p*4096 + (w<<10));
    }
    __syncthreads();
    short8 af[4], bfr[4];
    #pragma unroll
    for (int i=0;i<4;i++){
      af[i]  = *(const short8*)&As[(wr*64 + i*16 + (lane&15))*32 + (lane>>4)*8];
      bfr[i] = *(const short8*)&Bs[(wc*64 + i*16 + (lane&15))*32 + (lane>>4)*8];
    }
    #pragma unroll
    for (int i=0;i<4;i++)
      #pragma unroll
      for (int j=0;j<4;j++)
        acc[i][j] = __builtin_amdgcn_mfma_f32_16x16x32_bf16(af[i], bfr[j], acc[i][j], 0,0,0);
    __syncthreads();
  }
  int rbase = mt*128 + wr*64;
  int cbase = nloc + wc*64;
  #pragma unroll
  for (int j=0;j<4;j++){
    int col = cbase + j*16 + (lane&15);
    float bb = bp[col];
    #pragma unroll
    for (int i=0;i<4;i++){
      #pragma unroll
      for (int q=0;q<4;q++){
        int row = rbase + i*16 + (lane>>4)*4 + q;
        if (row < SQ_){
          u16 uv = f2bf(acc[i][j][q] + bb);
          if (which==0)      QL[(size_t)row*DIM + col] = uv;
          else if (which==1) KL[(size_t)row*DIM + col] = uv;
          else               VA[(size_t)(PAST_ + row)*DIM + col] = uv;
        }
      }
    }
  }
}

// ---------------- output GEMM (r14-verbatim: BK=32, 1D XCD grid) ----------------
__global__ __launch_bounds__(256) void gemm_out(
  const u16* __restrict__ A, const u16* __restrict__ W,
  const float* __restrict__ bias, float* __restrict__ out)
{
  __shared__ __align__(16) u16 As[4096];
  __shared__ __align__(16) u16 Bs[4096];
  // nwg=252: q=31,r=4 -> xcd<4 get 32 blocks, else 31
  int b = blockIdx.x;
  int xcd = b & 7, idx = b >> 3;
  int wg = (xcd < 4 ? xcd*32 : 128 + (xcd-4)*31) + idx;
  int mt = wg % 21, nt = wg / 21;
  int tid = threadIdx.x, lane = tid & 63, w = tid >> 6;
  int wr = w >> 1, wc = w & 1;
  int nloc = nt * 128;
  f32x4 acc[4][4];
  #pragma unroll
  for (int i=0;i<4;i++)
    #pragma unroll
    for (int j=0;j<4;j++) acc[i][j] = (f32x4){0.f,0.f,0.f,0.f};

  for (int k0 = 0; k0 < DIM; k0 += 32){
    #pragma unroll
    for (int p=0;p<2;p++){
      int e = (p*256 + tid) * 8;
      int r = e >> 5, c = e & 31;
      gload_lds16(A + (size_t)(mt*128 + r)*DIM + k0 + c, (char*)As + p*4096 + (w<<10));
      gload_lds16(W + (size_t)(nloc   + r)*DIM + k0 + c, (char*)Bs + p*4096 + (w<<10));
    }
    __syncthreads();
    short8 af[4], bfr[4];
    #pragma unroll
    for (int i=0;i<4;i++){
      af[i]  = *(const short8*)&As[(wr*64 + i*16 + (lane&15))*32 + (lane>>4)*8];
      bfr[i] = *(const short8*)&Bs[(wc*64 + i*16 + (lane&15))*32 + (lane>>4)*8];
    }
    #pragma unroll
    for (int i=0;i<4;i++)
      #pragma unroll
      for (int j=0;j<4;j++)
        acc[i][j] = __builtin_amdgcn_mfma_f32_16x16x32_bf16(af[i], bfr[j], acc[i][j], 0,0,0);
    __syncthreads();
  }
  int rbase = mt*128 + wr*64;
  int cbase = nloc + wc*64;
  #pragma unroll
  for (int j=0;j<4;j++){
    int col = cbase + j*16 + (lane&15);
    float bb = bias[col];
    #pragma unroll
    for (int i=0;i<4;i++){
      #pragma unroll
      for (int q=0;q<4;q++){
        int row = rbase + i*16 + (lane>>4)*4 + q;
        if (row < SQ_) out[(size_t)row*DIM + col] = acc[i][j][q] + bb;
      }
    }
  }
}

// ---------------- RMSNorm + RoPE (q and k fused: trig computed once) ----------------
// q path pre-scaled by log2(e)/sqrt(HD): attn logits land in exp2 domain.
__global__ __launch_bounds__(256) void norm_rope(
  const u16* __restrict__ QL, const u16* __restrict__ KL,
  const float* __restrict__ freqs, const float* __restrict__ gq, const float* __restrict__ gk,
  const int* __restrict__ cs,
  u16* __restrict__ Qout, u16* __restrict__ KAout)
{
  int s = blockIdx.x;
  int tid = threadIdx.x;
  const u16* srcq = QL + (size_t)s*DIM + tid*6;
  const u16* srck = KL + (size_t)s*DIM + tid*6;
  float yq[6], yk[6];
  #pragma unroll
  for (int t=0;t<6;t++){ yq[t] = bf2f(srcq[t]); yk[t] = bf2f(srck[t]); }
  float ssq = 0.f, ssk = 0.f;
  #pragma unroll
  for (int t=0;t<6;t++){ ssq += yq[t]*yq[t]; ssk += yk[t]*yk[t]; }
  for (int mk=1; mk<64; mk<<=1){ ssq += __shfl_xor(ssq, mk); ssk += __shfl_xor(ssk, mk); }
  __shared__ float redq[4], redk[4];
  if ((tid & 63) == 0){ redq[tid>>6] = ssq; redk[tid>>6] = ssk; }
  __syncthreads();
  float rnq = rsqrtf((redq[0]+redq[1]+redq[2]+redq[3]) * (1.0f/1536.0f) + 1e-6f)
            * 0.12752961954336302f;   // 1/sqrt(128) * log2(e)
  float rnk = rsqrtf((redk[0]+redk[1]+redk[2]+redk[3]) * (1.0f/1536.0f) + 1e-6f);
  const float* gqp = gq + tid*6;
  const float* gkp = gk + tid*6;
  int pos = cs[0] + s;
  int tpos = pos / 880, rem = pos % 880;
  int hh = rem / 40, wp = rem % 40;
  u16 ovq[6], ovk[6];
  #pragma unroll
  for (int pi=0; pi<3; pi++){
    int p = tid*3 + pi;
    int i = p & 63;
    int fr = (i < 22) ? tpos : ((i < 43) ? hh : wp);
    float ang = freqs[fr*64 + i];
    float sn, c;
    sincosf(ang, &sn, &c);
    float eq  = yq[pi*2]   * rnq * gqp[pi*2];
    float oq  = yq[pi*2+1] * rnq * gqp[pi*2+1];
    ovq[pi*2]   = f2bf(eq*c - oq*sn);
    ovq[pi*2+1] = f2bf(oq*c + eq*sn);
    float ek  = yk[pi*2]   * rnk * gkp[pi*2];
    float ok  = yk[pi*2+1] * rnk * gkp[pi*2+1];
    ovk[pi*2]   = f2bf(ek*c - ok*sn);
    ovk[pi*2+1] = f2bf(ok*c + ek*sn);
  }
  u16* dq = Qout  + (size_t)s*DIM + tid*6;
  u16* dk = KAout + (size_t)(PAST_ + s)*DIM + tid*6;
  #pragma unroll
  for (int t=0;t<6;t++){ dq[t] = ovq[t]; dk[t] = ovk[t]; }
}

// ---------------- flash attention (r14 verbatim: XCD-grouped 1D grid) ----------------
__global__ __launch_bounds__(256, 2) void attn(
  const u16* __restrict__ Qf, const u16* __restrict__ KA,
  const u16* __restrict__ VA, u16* __restrict__ OP, float* __restrict__ ML)
{
  __shared__ __align__(16) u16 Ks[2][64*128];   // [kv][d], XOR key (kv&7)<<4
  __shared__ __align__(16) u16 Vt[2][128*64];   // [d][kv], XOR key ((d&7)<<4)|(((d>>3)&1)<<3)
  int bid = blockIdx.x;
  int wid = (bid & 7) * 63 + (bid >> 3);        // XCD-grouped work id
  int qt = wid % 21;
  int hz = wid / 21;
  int h = hz % 12;
  int z = hz / 12;
  int tid = threadIdx.x, lane = tid & 63, w = tid >> 6;
  int g = lane >> 4, q = lane & 15;
  int qrow0 = qt*128 + w*32;
  int kvbeg = z ? 6656 : 0;
  int kvend = z ? LPAD : 6656;
  int c0 = (tid >> 4) << 3;
  int r0 = (tid & 15) << 2;

  short8 qa[2][4];
  #pragma unroll
  for (int cq=0;cq<2;cq++){
    const u16* qb = Qf + (size_t)(qrow0 + cq*16 + q)*DIM + h*HD + g*8;
    #pragma unroll
    for (int kt=0;kt<4;kt++) qa[cq][kt] = *(const short8*)(qb + kt*32);
  }
  f32x4 o[2][8];
  #pragma unroll
  for (int cq=0;cq<2;cq++)
    #pragma unroll
    for (int dt=0;dt<8;dt++) o[cq][dt] = (f32x4){0.f,0.f,0.f,0.f};
  float m[2] = {-1e30f,-1e30f};
  float l[2] = {0.f,0.f};

  auto stageK = [&](int kv0, u16* dK){
    #pragma unroll
    for (int p=0;p<4;p++){
      int e = w*2048 + p*512 + lane*8;
      int r = e >> 7;
      int bcol = (e & 127) << 1;
      int sb = bcol ^ ((r & 7) << 4);
      gload_lds16(KA + (size_t)(kv0 + r)*DIM + h*HD + (sb>>1),
                  (char*)dK + w*4096 + p*1024);
    }
  };
  auto loadV = [&](int kv0, short8* vr){
    const u16* vs = VA + (size_t)(kv0 + r0)*DIM + h*HD + c0;
    vr[0] = *(const short8*)(vs);
    vr[1] = *(const short8*)(vs + DIM);
    vr[2] = *(const short8*)(vs + 2*DIM);
    vr[3] = *(const short8*)(vs + 3*DIM);
  };
  auto writeVt = [&](u16* dV, short8* vr){
    #pragma unroll
    for (int j=0;j<8;j++){
      int d = c0 + j;
      int key = ((d & 7) << 4) | (((d >> 3) & 1) << 3);
      int off = d*128 + ((r0*2) ^ key);
      us4 pk; pk[0]=(u16)vr[0][j]; pk[1]=(u16)vr[1][j]; pk[2]=(u16)vr[2][j]; pk[3]=(u16)vr[3][j];
      *(us4*)((char*)dV + off) = pk;
    }
  };

  short8 vr[4];
  int cur = 0;
  // prologue: stage tile 0
  stageK(kvbeg, &Ks[0][0]);
  loadV(kvbeg, vr);
  writeVt(&Vt[0][0], vr);
  __syncthreads();

  for (int kv0 = kvbeg; kv0 < kvend; kv0 += 64){
    int nxt = kv0 + 64;
    bool has_next = nxt < kvend;
    // --- issue next-tile staging BEFORE compute (latency hides under MFMA/VALU) ---
    if (has_next){
      stageK(nxt, &Ks[cur^1][0]);
      loadV(nxt, vr);
    }
    // --- QK^T swapped: D[kv][q] ---
    f32x4 s4[2][4];
    #pragma unroll
    for (int cq=0;cq<2;cq++)
      #pragma unroll
      for (int ct=0;ct<4;ct++) s4[cq][ct] = (f32x4){0.f,0.f,0.f,0.f};
    const u16* ksb = &Ks[cur][0];
    __builtin_amdgcn_s_setprio(1);
    #pragma unroll
    for (int ct=0;ct<4;ct++){
      int row = ct*16 + q;
      int rbyte = row*256, sw = (row & 7) << 4;
      #pragma unroll
      for (int kt=0;kt<4;kt++){
        int b = (kt*64 + (g<<4)) ^ sw;
        short8 kb = *(const short8*)((const char*)ksb + rbyte + b);
        s4[0][ct] = __builtin_amdgcn_mfma_f32_16x16x32_bf16(kb, qa[0][kt], s4[0][ct], 0,0,0);
        s4[1][ct] = __builtin_amdgcn_mfma_f32_16x16x32_bf16(kb, qa[1][kt], s4[1][ct], 0,0,0);
      }
    }
    __builtin_amdgcn_s_setprio(0);
    // --- tail mask: kv = kv0 + ct*16 + g*4 + j ---
    if (kv0 + 64 > LTOT){
      #pragma unroll
      for (int ct=0;ct<4;ct++)
        #pragma unroll
        for (int j=0;j<4;j++)
          if (kv0 + ct*16 + g*4 + j >= LTOT){ s4[0][ct][j] = -1e30f; s4[1][ct][j] = -1e30f; }
    }
    // --- row max (max3-friendly triples) + defer-max (T13, THR=8) ---
    float rm[2];
    #pragma unroll
    for (int cq=0;cq<2;cq++){
      float a0 = fmaxf(fmaxf(s4[cq][0][0], s4[cq][0][1]), s4[cq][0][2]);
      float a1 = fmaxf(fmaxf(s4[cq][0][3], s4[cq][1][0]), s4[cq][1][1]);
      float a2 = fmaxf(fmaxf(s4[cq][1][2], s4[cq][1][3]), s4[cq][2][0]);
      float a3 = fmaxf(fmaxf(s4[cq][2][1], s4[cq][2][2]), s4[cq][2][3]);
      float a4 = fmaxf(fmaxf(s4[cq][3][0], s4[cq][3][1]), s4[cq][3][2]);
      float r_ = fmaxf(fmaxf(a0, a1), fmaxf(fmaxf(a2, a3), fmaxf(a4, s4[cq][3][3])));
      r_ = fmaxf(r_, __shfl_xor(r_, 16));
      r_ = fmaxf(r_, __shfl_xor(r_, 32));
      rm[cq] = r_;
    }
    if (__any((rm[0] > m[0]+8.f) | (rm[1] > m[1]+8.f))){
      #pragma unroll
      for (int cq=0;cq<2;cq++){
        float mn = fmaxf(m[cq], rm[cq]);
        float al = exp2f(m[cq] - mn);
        m[cq] = mn;
        l[cq] *= al;
        #pragma unroll
        for (int dt=0;dt<8;dt++){
          f32x4 t = o[cq][dt];
          t[0]*=al; t[1]*=al; t[2]*=al; t[3]*=al;
          o[cq][dt] = t;
        }
      }
    }
    // --- exp2 + cvt_pk pack into PV B-frags + row sum ---
    short4b pb[2][4];
    #pragma unroll
    for (int cq=0;cq<2;cq++){
      float rs = 0.f;
      #pragma unroll
      for (int ct=0;ct<4;ct++){
        float e0 = exp2f(s4[cq][ct][0] - m[cq]);
        float e1 = exp2f(s4[cq][ct][1] - m[cq]);
        float e2 = exp2f(s4[cq][ct][2] - m[cq]);
        float e3 = exp2f(s4[cq][ct][3] - m[cq]);
        rs += (e0 + e1) + (e2 + e3);
        u32x2 pw = { cvtpk_bf16(e0, e1), cvtpk_bf16(e2, e3) };
        pb[cq][ct] = __builtin_bit_cast(short4b, pw);
      }
      rs += __shfl_xor(rs, 16);
      rs += __shfl_xor(rs, 32);
      l[cq] += rs;
    }
    // --- PV via 16x16x16: o[d][q] += V^T[d][kv] · P^T[q][kv] ---
    const u16* vtb = &Vt[cur][0];
    __builtin_amdgcn_s_setprio(1);
    #pragma unroll
    for (int dt=0;dt<8;dt++){
      int d = dt*16 + q;
      int key = ((d & 7) << 4) | (((d >> 3) & 1) << 3);
      int rbyte = d*128;
      #pragma unroll
      for (int ct=0;ct<4;ct++){
        int b = (ct*32 + (g<<3)) ^ key;
        short4b va_ = *(const short4b*)((const char*)vtb + rbyte + b);
        o[0][dt] = mfma16(va_, pb[0][ct], o[0][dt]);
        o[1][dt] = mfma16(va_, pb[1][ct], o[1][dt]);
      }
    }
    __builtin_amdgcn_s_setprio(0);
    // --- finish staging: write Vt(t+1) (compiler waits vmcnt on vr), one barrier ---
    if (has_next){
      writeVt(&Vt[cur^1][0], vr);
      __syncthreads();
      cur ^= 1;
    }
  }
  // --- store UNNORMALIZED partial (bf16 via cvt_pk) + (m,l) per q-row ---
  #pragma unroll
  for (int cq=0;cq<2;cq++){
    int row = qrow0 + cq*16 + q;
    size_t ob = ((size_t)(z*SPAD + row)*NH + h)*HD;
    #pragma unroll
    for (int dt=0;dt<8;dt++){
      u32x2 pw = { cvtpk_bf16(o[cq][dt][0], o[cq][dt][1]),
                   cvtpk_bf16(o[cq][dt][2], o[cq][dt][3]) };
      *(u32x2*)&OP[ob + dt*16 + g*4] = pw;
    }
    if (g == 0){
      size_t mb = ((size_t)(z*SPAD + row)*NH + h)*2;
      ML[mb] = m[cq]; ML[mb+1] = l[cq];
    }
  }
}

// ---------------- merge kv-split partials (flat grid-stride) ----------------
__global__ void merge_attn(const u16* __restrict__ OP, const float* __restrict__ ML,
                           u16* __restrict__ AB)
{
  const int total = SQ_ * NH * HD;
  for (int e = blockIdx.x * 256 + threadIdx.x; e < total; e += gridDim.x * 256){
    int s = e / (NH*HD);
    int r = e - s*(NH*HD);
    int h = r >> 7;
    int d = r & 127;
    size_t i1 = ((size_t)s*NH + h)*2;
    size_t i2 = ((size_t)(SPAD + s)*NH + h)*2;
    float m1 = ML[i1], l1 = ML[i1+1];
    float m2 = ML[i2], l2 = ML[i2+1];
    float M = fmaxf(m1, m2);
    float e1 = exp2f(m1 - M), e2 = exp2f(m2 - M);
    float den = 1.0f / (l1*e1 + l2*e2);
    float o1 = bf2f(OP[((size_t)s*NH + h)*HD + d]);
    float o2 = bf2f(OP[((size_t)(SPAD + s)*NH + h)*HD + d]);
    AB[(size_t)s*DIM + h*HD + d] = f2bf((o1*e1 + o2*e2) * den);
  }
}

// ---------------- launch ----------------
extern "C" void kernel_launch(void* const* d_in, const int* in_sizes, int n_in,
                              void* d_out, int out_size, void* d_ws, size_t ws_size,
                              hipStream_t stream) {
  (void)in_sizes; (void)n_in; (void)out_size; (void)ws_size;
  const float* x    = (const float*)d_in[0];
  const float* freqs= (const float*)d_in[1];
  const float* ck   = (const float*)d_in[2];
  const float* cv   = (const float*)d_in[3];
  const float* Wq   = (const float*)d_in[4];
  const float* bq   = (const float*)d_in[5];
  const float* Wk   = (const float*)d_in[6];
  const float* bk   = (const float*)d_in[7];
  const float* Wv   = (const float*)d_in[8];
  const float* bv   = (const float*)d_in[9];
  const float* Wo   = (const float*)d_in[10];
  const float* bo   = (const float*)d_in[11];
  const float* gq   = (const float*)d_in[12];
  const float* gk   = (const float*)d_in[13];
  const int*   cs   = (const int*)d_in[14];
  float* out = (float*)d_out;
  char* ws = (char*)d_ws;

  u16* AB  = (u16*)(ws);                      // 8,257,536 (x_bf16 -> attn out)
  u16* Wb3 = (u16*)(ws + 8257536);            // 4,718,592
  u16* QL  = (u16*)(ws + 12976128);           // 8,257,536
  u16* KA  = (u16*)(ws + 21233664);           // 40,697,856
  u16* VA  = (u16*)(ws + 61931520);           // 40,697,856
  u16* Wb0 = (u16*)(ws + 102629376);
  u16* Wb1 = (u16*)(ws + 107347968);
  u16* Wb2 = (u16*)(ws + 112066560);
  u16* KL  = (u16*)(ws + 116785152);          // ends 124,895,232
  u16*   OP = (u16*)(ws + 102629376);         // 16,515,072 (2 x 2688 x 12 x 128 bf16)
  float* ML = (float*)(ws + 119144448);       // 516,096

  k_cvt4<<<dim3(2304,4), 256, 0, stream>>>(Wq, Wk, Wv, Wo, Wb0, Wb1, Wb2, Wb3, 589824);
  k_prep_x<<<4104, 256, 0, stream>>>(x, AB, QL + (size_t)SQ_*DIM);
  k_prep_kv<<<dim3(15912,2), 256, 0, stream>>>(ck, cv, KA, VA, 4073472);

  gemm_qkv<<<756, 256, 0, stream>>>(AB, Wb0, Wb1, Wb2, bq, bk, bv, QL, KL, VA);
  norm_rope<<<2640, 256, 0, stream>>>(QL, KL, freqs, gq, gk, cs, QL, KA);
  attn<<<504, 256, 0, stream>>>(QL, KA, VA, OP, ML);
  merge_attn<<<2048, 256, 0, stream>>>(OP, ML, AB);
  gemm_out<<<252, 256, 0, stream>>>(AB, Wb3, bo, out);
}